// Round 1
// baseline (12298.584 us; speedup 1.0000x reference)
//
#include <hip/hip_runtime.h>

#define NNODES 100000
#define NEDGES 1600000
#define NG 128
#define HID 64
#define INDIM 32
#define CAT 320   // HID*(L+1)
#define ODIM 32

__device__ __forceinline__ float bcast(float v, int lane) {
    return __uint_as_float(__builtin_amdgcn_readlane(__float_as_uint(v), lane));
}

// One wave (64 lanes) per node: X = x @ pre_w + pre_b ; XRES = X ; pool stage 0.
__global__ void pre_kernel(const float* __restrict__ xin, const int* __restrict__ batch,
                           const float* __restrict__ w, const float* __restrict__ b,
                           float* __restrict__ X, float* __restrict__ XRES,
                           float* __restrict__ G) {
    int gid  = blockIdx.x * blockDim.x + threadIdx.x;
    int node = gid >> 6;
    int lane = threadIdx.x & 63;
    if (node >= NNODES) return;
    float in  = (lane < INDIM) ? xin[node * INDIM + lane] : 0.f;
    float acc = b[lane];
#pragma unroll
    for (int k = 0; k < INDIM; ++k)
        acc = fmaf(bcast(in, k), w[k * HID + lane], acc);
    X[node * HID + lane]    = acc;
    XRES[node * HID + lane] = acc;
    atomicAdd(&G[batch[node] * CAT + lane], acc);   // emb[0] pooled (no relu)
}

// 16 threads per edge; each thread moves a float4 and does 4 atomic adds.
__global__ void scatter_kernel(const float4* __restrict__ X4, const int* __restrict__ ei,
                               float* __restrict__ AGG) {
    int t = blockIdx.x * blockDim.x + threadIdx.x;
    int e = t >> 4;
    if (e >= NEDGES) return;
    int q   = t & 15;
    int src = ei[e];
    int dst = ei[NEDGES + e];
    float4 v = X4[src * 16 + q];
    float* p = AGG + dst * HID + q * 4;
    atomicAdd(p + 0, v.x);
    atomicAdd(p + 1, v.y);
    atomicAdd(p + 2, v.z);
    atomicAdd(p + 3, v.w);
}

// One wave per node (grid-stride): h = relu((X+AGG)@w1+b1)@w2+b2 [+XRES];
// X = relu(h); pool stage `stage`.
__global__ void mlp_kernel(float* __restrict__ X, const float* __restrict__ AGG,
                           float* __restrict__ XRES, float* __restrict__ G,
                           const int* __restrict__ batch,
                           const float* __restrict__ w1, const float* __restrict__ b1,
                           const float* __restrict__ w2, const float* __restrict__ b2,
                           int do_res, int stage) {
    __shared__ float sw1[HID * HID];
    __shared__ float sw2[HID * HID];
    for (int i = threadIdx.x; i < HID * HID; i += blockDim.x) {
        sw1[i] = w1[i];
        sw2[i] = w2[i];
    }
    __syncthreads();
    int lane          = threadIdx.x & 63;
    int waveInBlock   = threadIdx.x >> 6;
    int wavesPerBlock = blockDim.x >> 6;
    int wave          = blockIdx.x * wavesPerBlock + waveInBlock;
    int nWaves        = gridDim.x * wavesPerBlock;
    float bb1 = b1[lane], bb2 = b2[lane];
    for (int node = wave; node < NNODES; node += nWaves) {
        float in   = X[node * HID + lane] + AGG[node * HID + lane];
        float acc1 = bb1;
#pragma unroll
        for (int k = 0; k < HID; ++k)
            acc1 = fmaf(bcast(in, k), sw1[k * HID + lane], acc1);
        float h1   = fmaxf(acc1, 0.f);
        float acc2 = bb2;
#pragma unroll
        for (int k = 0; k < HID; ++k)
            acc2 = fmaf(bcast(h1, k), sw2[k * HID + lane], acc2);
        if (do_res) {
            acc2 += XRES[node * HID + lane];
            XRES[node * HID + lane] = acc2;
        }
        float xn = fmaxf(acc2, 0.f);
        X[node * HID + lane] = xn;
        atomicAdd(&G[batch[node] * CAT + stage * HID + lane], xn);
    }
}

// One block (64 threads) per graph: out[g] = sum |postMLP(gq) - postMLP(gc)|.
__global__ void post_kernel(const float* __restrict__ GQ, const float* __restrict__ GC,
                            const float* __restrict__ w1, const float* __restrict__ b1,
                            const float* __restrict__ w2, const float* __restrict__ b2,
                            float* __restrict__ out) {
    int g    = blockIdx.x;
    int lane = threadIdx.x;
    __shared__ float h1q[HID], h1c[HID];
    float aq = b1[lane], ac = b1[lane];
    for (int k = 0; k < CAT; ++k) {
        float w = w1[k * HID + lane];
        aq = fmaf(GQ[g * CAT + k], w, aq);
        ac = fmaf(GC[g * CAT + k], w, ac);
    }
    h1q[lane] = fmaxf(aq, 0.f);
    h1c[lane] = fmaxf(ac, 0.f);
    __syncthreads();
    float s = 0.f;
    if (lane < ODIM) {
        float oq = b2[lane], oc = b2[lane];
        for (int k = 0; k < HID; ++k) {
            float w = w2[k * ODIM + lane];
            oq = fmaf(h1q[k], w, oq);
            oc = fmaf(h1c[k], w, oc);
        }
        s = fabsf(oq - oc);
    }
    for (int off = 16; off; off >>= 1) s += __shfl_down(s, off, 64);
    if (lane == 0) out[g] = s;
}

extern "C" void kernel_launch(void* const* d_in, const int* in_sizes, int n_in,
                              void* d_out, int out_size, void* d_ws, size_t ws_size,
                              hipStream_t stream) {
    const float* x_q     = (const float*)d_in[0];
    const int*   ei_q    = (const int*)d_in[1];
    const int*   batch_q = (const int*)d_in[2];
    const float* x_c     = (const float*)d_in[3];
    const int*   ei_c    = (const int*)d_in[4];
    const int*   batch_c = (const int*)d_in[5];
    const float* pre_w   = (const float*)d_in[6];
    const float* pre_b   = (const float*)d_in[7];
    const float* conv_w1 = (const float*)d_in[8];
    const float* conv_b1 = (const float*)d_in[9];
    const float* conv_w2 = (const float*)d_in[10];
    const float* conv_b2 = (const float*)d_in[11];
    const float* post_w1 = (const float*)d_in[12];
    const float* post_b1 = (const float*)d_in[13];
    const float* post_w2 = (const float*)d_in[14];
    const float* post_b2 = (const float*)d_in[15];

    float* ws   = (float*)d_ws;
    float* X    = ws;                      // NNODES*HID
    float* AGG  = X + NNODES * HID;        // NNODES*HID
    float* XRES = AGG + NNODES * HID;      // NNODES*HID
    float* GQ   = XRES + NNODES * HID;     // NG*CAT
    float* GC   = GQ + NG * CAT;           // NG*CAT

    hipMemsetAsync(GQ, 0, 2 * NG * CAT * sizeof(float), stream);

    for (int side = 0; side < 2; ++side) {
        const float* xin   = side ? x_c : x_q;
        const int*   ei    = side ? ei_c : ei_q;
        const int*   batch = side ? batch_c : batch_q;
        float*       G     = side ? GC : GQ;

        pre_kernel<<<(NNODES + 3) / 4, 256, 0, stream>>>(xin, batch, pre_w, pre_b, X, XRES, G);

        for (int l = 0; l < 4; ++l) {
            hipMemsetAsync(AGG, 0, (size_t)NNODES * HID * sizeof(float), stream);
            scatter_kernel<<<(NEDGES * 16) / 256, 256, 0, stream>>>((const float4*)X, ei, AGG);
            mlp_kernel<<<1024, 256, 0, stream>>>(X, AGG, XRES, G, batch,
                                                 conv_w1 + l * HID * HID, conv_b1 + l * HID,
                                                 conv_w2 + l * HID * HID, conv_b2 + l * HID,
                                                 l & 1, l + 1);
        }
    }

    post_kernel<<<NG, 64, 0, stream>>>(GQ, GC, post_w1, post_b1, post_w2, post_b2,
                                       (float*)d_out);
}

// Round 2
// 6993.766 us; speedup vs baseline: 1.7585x; 1.7585x over previous
//
#include <hip/hip_runtime.h>

#define NNODES 100000
#define NEDGES 1600000
#define NG 128
#define HID 64
#define INDIM 32
#define CAT 320   // HID*(L+1)
#define ODIM 32

#define BSH 7                              // nodes per bucket = 128
#define NPB 128
#define NB ((NNODES + NPB - 1) / NPB)      // 782
#define CHUNK 4096
#define NCHUNKBLKS ((NEDGES + CHUNK - 1) / CHUNK)   // 391

__device__ __forceinline__ float bcast(float v, int lane) {
    return __uint_as_float(__builtin_amdgcn_readlane(__float_as_uint(v), lane));
}

// ---------- edge binning (once per side, reused across 4 layers) ----------

__global__ void hist_kernel(const int* __restrict__ ei, int* __restrict__ counts) {
    __shared__ int h[NB];
    for (int i = threadIdx.x; i < NB; i += blockDim.x) h[i] = 0;
    __syncthreads();
    int stride = gridDim.x * blockDim.x;
    for (int e = blockIdx.x * blockDim.x + threadIdx.x; e < NEDGES; e += stride)
        atomicAdd(&h[ei[NEDGES + e] >> BSH], 1);
    __syncthreads();
    for (int i = threadIdx.x; i < NB; i += blockDim.x)
        if (h[i]) atomicAdd(&counts[i], h[i]);
}

__global__ void scan_kernel(const int* __restrict__ counts, int* __restrict__ start,
                            int* __restrict__ cursor) {
    __shared__ int s[1024];
    int tid = threadIdx.x;
    int own = (tid < NB) ? counts[tid] : 0;
    s[tid] = own;
    for (int off = 1; off < 1024; off <<= 1) {
        __syncthreads();
        int v = (tid >= off) ? s[tid - off] : 0;
        __syncthreads();
        s[tid] += v;
    }
    __syncthreads();
    if (tid < NB) {
        int excl = s[tid] - own;
        start[tid]  = excl;
        cursor[tid] = excl;
        if (tid == NB - 1) start[NB] = s[tid];
    }
}

__global__ void reorder_kernel(const int* __restrict__ ei, int* __restrict__ cursor,
                               unsigned int* __restrict__ packed) {
    __shared__ int h[NB], base[NB], lpos[NB];
    int e0 = blockIdx.x * CHUNK;
    int e1 = min(e0 + CHUNK, NEDGES);
    for (int i = threadIdx.x; i < NB; i += blockDim.x) { h[i] = 0; lpos[i] = 0; }
    __syncthreads();
    for (int e = e0 + threadIdx.x; e < e1; e += blockDim.x)
        atomicAdd(&h[ei[NEDGES + e] >> BSH], 1);
    __syncthreads();
    for (int i = threadIdx.x; i < NB; i += blockDim.x)
        if (h[i]) base[i] = atomicAdd(&cursor[i], h[i]);
    __syncthreads();
    for (int e = e0 + threadIdx.x; e < e1; e += blockDim.x) {
        int dst = ei[NEDGES + e];
        int b   = dst >> BSH;
        int p   = base[b] + atomicAdd(&lpos[b], 1);
        packed[p] = (unsigned)ei[e] | ((unsigned)(dst & (NPB - 1)) << 20);
    }
}

// ---------- LDS-accumulated scatter: one block per 128-node bucket ----------

__global__ void __launch_bounds__(512) scatter_kernel(
        const float* __restrict__ X, const unsigned int* __restrict__ packed,
        const int* __restrict__ start, float* __restrict__ AGG) {
    __shared__ float tile[NPB * HID];
    int b = blockIdx.x;
    for (int i = threadIdx.x; i < NPB * HID; i += blockDim.x) tile[i] = 0.f;
    __syncthreads();
    int lane = threadIdx.x & 63;
    int wave = threadIdx.x >> 6;
    int nw   = blockDim.x >> 6;
    int e1   = start[b + 1];
    for (int e = start[b] + wave; e < e1; e += nw) {
        unsigned u = packed[e];
        int src  = u & 0xFFFFF;
        int ldst = u >> 20;
        atomicAdd(&tile[(ldst << 6) + lane], X[(src << 6) + lane]);
    }
    __syncthreads();
    int node0  = b << BSH;
    int nvalid = min(NPB, NNODES - node0);
    for (int i = threadIdx.x; i < nvalid * HID; i += blockDim.x)
        AGG[node0 * HID + i] = tile[i];
}

// ---------- dense pieces ----------

__global__ void pre_kernel(const float* __restrict__ xin, const int* __restrict__ batch,
                           const float* __restrict__ w, const float* __restrict__ b,
                           float* __restrict__ X, float* __restrict__ XRES,
                           float* __restrict__ G) {
    int gid  = blockIdx.x * blockDim.x + threadIdx.x;
    int node = gid >> 6;
    int lane = threadIdx.x & 63;
    if (node >= NNODES) return;
    float in  = (lane < INDIM) ? xin[node * INDIM + lane] : 0.f;
    float acc = b[lane];
#pragma unroll
    for (int k = 0; k < INDIM; ++k)
        acc = fmaf(bcast(in, k), w[k * HID + lane], acc);
    X[node * HID + lane]    = acc;
    XRES[node * HID + lane] = acc;
    atomicAdd(&G[batch[node] * CAT + lane], acc);
}

__global__ void mlp_kernel(float* __restrict__ X, const float* __restrict__ AGG,
                           float* __restrict__ XRES, float* __restrict__ G,
                           const int* __restrict__ batch,
                           const float* __restrict__ w1, const float* __restrict__ b1,
                           const float* __restrict__ w2, const float* __restrict__ b2,
                           int do_res, int stage) {
    __shared__ float sw1[HID * HID];
    __shared__ float sw2[HID * HID];
    for (int i = threadIdx.x; i < HID * HID; i += blockDim.x) {
        sw1[i] = w1[i];
        sw2[i] = w2[i];
    }
    __syncthreads();
    int lane          = threadIdx.x & 63;
    int waveInBlock   = threadIdx.x >> 6;
    int wavesPerBlock = blockDim.x >> 6;
    int wave          = blockIdx.x * wavesPerBlock + waveInBlock;
    int nWaves        = gridDim.x * wavesPerBlock;
    float bb1 = b1[lane], bb2 = b2[lane];
    for (int node = wave; node < NNODES; node += nWaves) {
        float in   = X[node * HID + lane] + AGG[node * HID + lane];
        float acc1 = bb1;
#pragma unroll
        for (int k = 0; k < HID; ++k)
            acc1 = fmaf(bcast(in, k), sw1[k * HID + lane], acc1);
        float h1   = fmaxf(acc1, 0.f);
        float acc2 = bb2;
#pragma unroll
        for (int k = 0; k < HID; ++k)
            acc2 = fmaf(bcast(h1, k), sw2[k * HID + lane], acc2);
        if (do_res) {
            acc2 += XRES[node * HID + lane];
            XRES[node * HID + lane] = acc2;
        }
        float xn = fmaxf(acc2, 0.f);
        X[node * HID + lane] = xn;
        atomicAdd(&G[batch[node] * CAT + stage * HID + lane], xn);
    }
}

__global__ void post_kernel(const float* __restrict__ GQ, const float* __restrict__ GC,
                            const float* __restrict__ w1, const float* __restrict__ b1,
                            const float* __restrict__ w2, const float* __restrict__ b2,
                            float* __restrict__ out) {
    int g    = blockIdx.x;
    int lane = threadIdx.x;
    __shared__ float h1q[HID], h1c[HID];
    float aq = b1[lane], ac = b1[lane];
    for (int k = 0; k < CAT; ++k) {
        float w = w1[k * HID + lane];
        aq = fmaf(GQ[g * CAT + k], w, aq);
        ac = fmaf(GC[g * CAT + k], w, ac);
    }
    h1q[lane] = fmaxf(aq, 0.f);
    h1c[lane] = fmaxf(ac, 0.f);
    __syncthreads();
    float s = 0.f;
    if (lane < ODIM) {
        float oq = b2[lane], oc = b2[lane];
        for (int k = 0; k < HID; ++k) {
            float w = w2[k * ODIM + lane];
            oq = fmaf(h1q[k], w, oq);
            oc = fmaf(h1c[k], w, oc);
        }
        s = fabsf(oq - oc);
    }
    for (int off = 16; off; off >>= 1) s += __shfl_down(s, off, 64);
    if (lane == 0) out[g] = s;
}

extern "C" void kernel_launch(void* const* d_in, const int* in_sizes, int n_in,
                              void* d_out, int out_size, void* d_ws, size_t ws_size,
                              hipStream_t stream) {
    const float* x_q     = (const float*)d_in[0];
    const int*   ei_q    = (const int*)d_in[1];
    const int*   batch_q = (const int*)d_in[2];
    const float* x_c     = (const float*)d_in[3];
    const int*   ei_c    = (const int*)d_in[4];
    const int*   batch_c = (const int*)d_in[5];
    const float* pre_w   = (const float*)d_in[6];
    const float* pre_b   = (const float*)d_in[7];
    const float* conv_w1 = (const float*)d_in[8];
    const float* conv_b1 = (const float*)d_in[9];
    const float* conv_w2 = (const float*)d_in[10];
    const float* conv_b2 = (const float*)d_in[11];
    const float* post_w1 = (const float*)d_in[12];
    const float* post_b1 = (const float*)d_in[13];
    const float* post_w2 = (const float*)d_in[14];
    const float* post_b2 = (const float*)d_in[15];

    float* ws   = (float*)d_ws;
    float* X    = ws;                       // NNODES*HID
    float* AGG  = X + NNODES * HID;         // NNODES*HID
    float* XRES = AGG + NNODES * HID;       // NNODES*HID
    float* GQ   = XRES + NNODES * HID;      // NG*CAT
    float* GC   = GQ + NG * CAT;            // NG*CAT
    int*   counts = (int*)(GC + NG * CAT);  // NB
    int*   start  = counts + NB;            // NB+1
    int*   cursor = start + NB + 1;         // NB
    unsigned int* packed = (unsigned int*)(cursor + NB);  // NEDGES

    hipMemsetAsync(GQ, 0, 2 * NG * CAT * sizeof(float), stream);

    for (int side = 0; side < 2; ++side) {
        const float* xin   = side ? x_c : x_q;
        const int*   ei    = side ? ei_c : ei_q;
        const int*   batch = side ? batch_c : batch_q;
        float*       G     = side ? GC : GQ;

        hipMemsetAsync(counts, 0, NB * sizeof(int), stream);
        hist_kernel<<<256, 256, 0, stream>>>(ei, counts);
        scan_kernel<<<1, 1024, 0, stream>>>(counts, start, cursor);
        reorder_kernel<<<NCHUNKBLKS, 256, 0, stream>>>(ei, cursor, packed);

        pre_kernel<<<(NNODES + 3) / 4, 256, 0, stream>>>(xin, batch, pre_w, pre_b, X, XRES, G);

        for (int l = 0; l < 4; ++l) {
            scatter_kernel<<<NB, 512, 0, stream>>>(X, packed, start, AGG);
            mlp_kernel<<<1024, 256, 0, stream>>>(X, AGG, XRES, G, batch,
                                                 conv_w1 + l * HID * HID, conv_b1 + l * HID,
                                                 conv_w2 + l * HID * HID, conv_b2 + l * HID,
                                                 l & 1, l + 1);
        }
    }

    post_kernel<<<NG, 64, 0, stream>>>(GQ, GC, post_w1, post_b1, post_w2, post_b2,
                                       (float*)d_out);
}

// Round 3
// 6904.947 us; speedup vs baseline: 1.7811x; 1.0129x over previous
//
#include <hip/hip_runtime.h>

#define NNODES 100000
#define NEDGES 1600000
#define NG 128
#define HID 64
#define INDIM 32
#define CAT 320   // HID*(L+1)
#define ODIM 32

#define BSH 7                              // nodes per bucket = 128
#define NPB 128
#define NB ((NNODES + NPB - 1) / NPB)      // 782
#define CHUNK 4096
#define NCHUNKBLKS ((NEDGES + CHUNK - 1) / CHUNK)   // 391

__device__ __forceinline__ float bcast(float v, int lane) {
    return __uint_as_float(__builtin_amdgcn_readlane(__float_as_uint(v), lane));
}
__device__ __forceinline__ unsigned bcast_u(unsigned v, int lane) {
    return __builtin_amdgcn_readlane(v, lane);
}

// ---------- edge binning (once per side, reused across 4 layers) ----------

__global__ void hist_kernel(const int* __restrict__ ei, int* __restrict__ counts) {
    __shared__ int h[NB];
    for (int i = threadIdx.x; i < NB; i += blockDim.x) h[i] = 0;
    __syncthreads();
    int stride = gridDim.x * blockDim.x;
    for (int e = blockIdx.x * blockDim.x + threadIdx.x; e < NEDGES; e += stride)
        atomicAdd(&h[ei[NEDGES + e] >> BSH], 1);
    __syncthreads();
    for (int i = threadIdx.x; i < NB; i += blockDim.x)
        if (h[i]) atomicAdd(&counts[i], h[i]);
}

__global__ void scan_kernel(const int* __restrict__ counts, int* __restrict__ start,
                            int* __restrict__ cursor) {
    __shared__ int s[1024];
    int tid = threadIdx.x;
    int own = (tid < NB) ? counts[tid] : 0;
    s[tid] = own;
    for (int off = 1; off < 1024; off <<= 1) {
        __syncthreads();
        int v = (tid >= off) ? s[tid - off] : 0;
        __syncthreads();
        s[tid] += v;
    }
    __syncthreads();
    if (tid < NB) {
        int excl = s[tid] - own;
        start[tid]  = excl;
        cursor[tid] = excl;
        if (tid == NB - 1) start[NB] = s[tid];
    }
}

__global__ void reorder_kernel(const int* __restrict__ ei, int* __restrict__ cursor,
                               unsigned int* __restrict__ packed) {
    __shared__ int h[NB], base[NB], lpos[NB];
    int e0 = blockIdx.x * CHUNK;
    int e1 = min(e0 + CHUNK, NEDGES);
    for (int i = threadIdx.x; i < NB; i += blockDim.x) { h[i] = 0; lpos[i] = 0; }
    __syncthreads();
    for (int e = e0 + threadIdx.x; e < e1; e += blockDim.x)
        atomicAdd(&h[ei[NEDGES + e] >> BSH], 1);
    __syncthreads();
    for (int i = threadIdx.x; i < NB; i += blockDim.x)
        if (h[i]) base[i] = atomicAdd(&cursor[i], h[i]);
    __syncthreads();
    for (int e = e0 + threadIdx.x; e < e1; e += blockDim.x) {
        int dst = ei[NEDGES + e];
        int b   = dst >> BSH;
        int p   = base[b] + atomicAdd(&lpos[b], 1);
        packed[p] = (unsigned)ei[e] | ((unsigned)(dst & (NPB - 1)) << 20);
    }
}

// ---------- LDS-accumulated scatter with 8-deep gather pipeline ----------

__global__ void __launch_bounds__(512) scatter_kernel(
        const float* __restrict__ X, const unsigned int* __restrict__ packed,
        const int* __restrict__ start, float* __restrict__ AGG) {
    __shared__ float tile[NPB * HID];
    int b = blockIdx.x;
    for (int i = threadIdx.x; i < NPB * HID; i += blockDim.x) tile[i] = 0.f;
    __syncthreads();
    int lane = threadIdx.x & 63;
    int wave = threadIdx.x >> 6;
    int nw   = blockDim.x >> 6;
    int eb   = start[b];
    int ee   = start[b + 1];
    // each wave grabs 64-edge batches; lane i holds edge base+i's descriptor
    for (int base = eb + wave * 64; base < ee; base += nw * 64) {
        int nv = min(64, ee - base);
        unsigned u = (base + lane < ee) ? packed[base + lane] : 0u;
        if (nv == 64) {
#pragma unroll
            for (int k = 0; k < 64; k += 8) {
                float v[8];
                int   ld[8];
#pragma unroll
                for (int j = 0; j < 8; ++j) {
                    unsigned uj = bcast_u(u, k + j);
                    v[j]  = X[((uj & 0xFFFFFu) << 6) + lane];
                    ld[j] = (int)(uj >> 20);
                }
#pragma unroll
                for (int j = 0; j < 8; ++j)
                    atomicAdd(&tile[(ld[j] << 6) + lane], v[j]);
            }
        } else {
            for (int k = 0; k < nv; ++k) {
                unsigned uj = bcast_u(u, k);
                float vv = X[((uj & 0xFFFFFu) << 6) + lane];
                atomicAdd(&tile[((int)(uj >> 20) << 6) + lane], vv);
            }
        }
    }
    __syncthreads();
    int node0  = b << BSH;
    int nvalid = min(NPB, NNODES - node0);
    for (int i = threadIdx.x; i < nvalid * HID; i += blockDim.x)
        AGG[node0 * HID + i] = tile[i];
}

// ---------- dense pieces ----------

__global__ void pre_kernel(const float* __restrict__ xin, const int* __restrict__ batch,
                           const float* __restrict__ w, const float* __restrict__ b,
                           float* __restrict__ X, float* __restrict__ XRES,
                           float* __restrict__ G) {
    int gid  = blockIdx.x * blockDim.x + threadIdx.x;
    int node = gid >> 6;
    int lane = threadIdx.x & 63;
    if (node >= NNODES) return;
    float in  = (lane < INDIM) ? xin[node * INDIM + lane] : 0.f;
    float acc = b[lane];
#pragma unroll
    for (int k = 0; k < INDIM; ++k)
        acc = fmaf(bcast(in, k), w[k * HID + lane], acc);
    X[node * HID + lane]    = acc;
    XRES[node * HID + lane] = acc;
    atomicAdd(&G[batch[node] * CAT + lane], acc);
}

__global__ void mlp_kernel(float* __restrict__ X, const float* __restrict__ AGG,
                           float* __restrict__ XRES, float* __restrict__ G,
                           const int* __restrict__ batch,
                           const float* __restrict__ w1, const float* __restrict__ b1,
                           const float* __restrict__ w2, const float* __restrict__ b2,
                           int do_res, int stage) {
    __shared__ float sw1[HID * HID];
    __shared__ float sw2[HID * HID];
    for (int i = threadIdx.x; i < HID * HID; i += blockDim.x) {
        sw1[i] = w1[i];
        sw2[i] = w2[i];
    }
    __syncthreads();
    int lane          = threadIdx.x & 63;
    int waveInBlock   = threadIdx.x >> 6;
    int wavesPerBlock = blockDim.x >> 6;
    int wave          = blockIdx.x * wavesPerBlock + waveInBlock;
    int nWaves        = gridDim.x * wavesPerBlock;
    float bb1 = b1[lane], bb2 = b2[lane];
    for (int node = wave; node < NNODES; node += nWaves) {
        float in   = X[node * HID + lane] + AGG[node * HID + lane];
        float acc1 = bb1;
#pragma unroll
        for (int k = 0; k < HID; ++k)
            acc1 = fmaf(bcast(in, k), sw1[k * HID + lane], acc1);
        float h1   = fmaxf(acc1, 0.f);
        float acc2 = bb2;
#pragma unroll
        for (int k = 0; k < HID; ++k)
            acc2 = fmaf(bcast(h1, k), sw2[k * HID + lane], acc2);
        if (do_res) {
            acc2 += XRES[node * HID + lane];
            XRES[node * HID + lane] = acc2;
        }
        float xn = fmaxf(acc2, 0.f);
        X[node * HID + lane] = xn;
        atomicAdd(&G[batch[node] * CAT + stage * HID + lane], xn);
    }
}

__global__ void post_kernel(const float* __restrict__ GQ, const float* __restrict__ GC,
                            const float* __restrict__ w1, const float* __restrict__ b1,
                            const float* __restrict__ w2, const float* __restrict__ b2,
                            float* __restrict__ out) {
    int g    = blockIdx.x;
    int lane = threadIdx.x;
    __shared__ float h1q[HID], h1c[HID];
    float aq = b1[lane], ac = b1[lane];
    for (int k = 0; k < CAT; ++k) {
        float w = w1[k * HID + lane];
        aq = fmaf(GQ[g * CAT + k], w, aq);
        ac = fmaf(GC[g * CAT + k], w, ac);
    }
    h1q[lane] = fmaxf(aq, 0.f);
    h1c[lane] = fmaxf(ac, 0.f);
    __syncthreads();
    float s = 0.f;
    if (lane < ODIM) {
        float oq = b2[lane], oc = b2[lane];
        for (int k = 0; k < HID; ++k) {
            float w = w2[k * ODIM + lane];
            oq = fmaf(h1q[k], w, oq);
            oc = fmaf(h1c[k], w, oc);
        }
        s = fabsf(oq - oc);
    }
    for (int off = 16; off; off >>= 1) s += __shfl_down(s, off, 64);
    if (lane == 0) out[g] = s;
}

extern "C" void kernel_launch(void* const* d_in, const int* in_sizes, int n_in,
                              void* d_out, int out_size, void* d_ws, size_t ws_size,
                              hipStream_t stream) {
    const float* x_q     = (const float*)d_in[0];
    const int*   ei_q    = (const int*)d_in[1];
    const int*   batch_q = (const int*)d_in[2];
    const float* x_c     = (const float*)d_in[3];
    const int*   ei_c    = (const int*)d_in[4];
    const int*   batch_c = (const int*)d_in[5];
    const float* pre_w   = (const float*)d_in[6];
    const float* pre_b   = (const float*)d_in[7];
    const float* conv_w1 = (const float*)d_in[8];
    const float* conv_b1 = (const float*)d_in[9];
    const float* conv_w2 = (const float*)d_in[10];
    const float* conv_b2 = (const float*)d_in[11];
    const float* post_w1 = (const float*)d_in[12];
    const float* post_b1 = (const float*)d_in[13];
    const float* post_w2 = (const float*)d_in[14];
    const float* post_b2 = (const float*)d_in[15];

    float* ws   = (float*)d_ws;
    float* X    = ws;                       // NNODES*HID
    float* AGG  = X + NNODES * HID;         // NNODES*HID
    float* XRES = AGG + NNODES * HID;       // NNODES*HID
    float* GQ   = XRES + NNODES * HID;      // NG*CAT
    float* GC   = GQ + NG * CAT;            // NG*CAT
    int*   counts = (int*)(GC + NG * CAT);  // NB
    int*   start  = counts + NB;            // NB+1
    int*   cursor = start + NB + 1;         // NB
    unsigned int* packed = (unsigned int*)(cursor + NB);  // NEDGES

    hipMemsetAsync(GQ, 0, 2 * NG * CAT * sizeof(float), stream);

    for (int side = 0; side < 2; ++side) {
        const float* xin   = side ? x_c : x_q;
        const int*   ei    = side ? ei_c : ei_q;
        const int*   batch = side ? batch_c : batch_q;
        float*       G     = side ? GC : GQ;

        hipMemsetAsync(counts, 0, NB * sizeof(int), stream);
        hist_kernel<<<256, 256, 0, stream>>>(ei, counts);
        scan_kernel<<<1, 1024, 0, stream>>>(counts, start, cursor);
        reorder_kernel<<<NCHUNKBLKS, 256, 0, stream>>>(ei, cursor, packed);

        pre_kernel<<<(NNODES + 3) / 4, 256, 0, stream>>>(xin, batch, pre_w, pre_b, X, XRES, G);

        for (int l = 0; l < 4; ++l) {
            scatter_kernel<<<NB, 512, 0, stream>>>(X, packed, start, AGG);
            mlp_kernel<<<1024, 256, 0, stream>>>(X, AGG, XRES, G, batch,
                                                 conv_w1 + l * HID * HID, conv_b1 + l * HID,
                                                 conv_w2 + l * HID * HID, conv_b2 + l * HID,
                                                 l & 1, l + 1);
        }
    }

    post_kernel<<<NG, 64, 0, stream>>>(GQ, GC, post_w1, post_b1, post_w2, post_b2,
                                       (float*)d_out);
}

// Round 4
// 5756.362 us; speedup vs baseline: 2.1365x; 1.1995x over previous
//
#include <hip/hip_runtime.h>

#define NNODES 100000
#define NEDGES 1600000
#define NG 128
#define HID 64
#define INDIM 32
#define CAT 320   // HID*(L+1)
#define ODIM 32

#define BSH 6                              // nodes per bucket = 64
#define NPB 64
#define NB ((NNODES + NPB - 1) / NPB)      // 1563
#define CHUNK 4096
#define NCHUNKBLKS ((NEDGES + CHUNK - 1) / CHUNK)   // 391

__device__ __forceinline__ float bcast(float v, int lane) {
    return __uint_as_float(__builtin_amdgcn_readlane(__float_as_uint(v), lane));
}
__device__ __forceinline__ unsigned bcast_u(unsigned v, int lane) {
    return __builtin_amdgcn_readlane(v, lane);
}

// ---------- edge binning (once per side, reused across 4 layers) ----------

__global__ void hist_kernel(const int* __restrict__ ei, int* __restrict__ counts) {
    __shared__ int h[NB];
    for (int i = threadIdx.x; i < NB; i += blockDim.x) h[i] = 0;
    __syncthreads();
    int stride = gridDim.x * blockDim.x;
    for (int e = blockIdx.x * blockDim.x + threadIdx.x; e < NEDGES; e += stride)
        atomicAdd(&h[ei[NEDGES + e] >> BSH], 1);
    __syncthreads();
    for (int i = threadIdx.x; i < NB; i += blockDim.x)
        if (h[i]) atomicAdd(&counts[i], h[i]);
}

// 1024 threads, 2 buckets per thread (NB=1563 <= 2048)
__global__ void scan_kernel(const int* __restrict__ counts, int* __restrict__ start,
                            int* __restrict__ cursor) {
    __shared__ int s[1024];
    int t  = threadIdx.x;
    int i0 = 2 * t, i1 = 2 * t + 1;
    int a = (i0 < NB) ? counts[i0] : 0;
    int b = (i1 < NB) ? counts[i1] : 0;
    int psum = a + b;
    s[t] = psum;
    for (int off = 1; off < 1024; off <<= 1) {
        __syncthreads();
        int v = (t >= off) ? s[t - off] : 0;
        __syncthreads();
        s[t] += v;
    }
    __syncthreads();
    int excl = s[t] - psum;
    if (i0 < NB) { start[i0] = excl;     cursor[i0] = excl; }
    if (i1 < NB) { start[i1] = excl + a; cursor[i1] = excl + a; }
    if (t == 1023) start[NB] = s[t];
}

__global__ void reorder_kernel(const int* __restrict__ ei, int* __restrict__ cursor,
                               unsigned int* __restrict__ packed) {
    __shared__ int h[NB], base[NB], lpos[NB];
    int e0 = blockIdx.x * CHUNK;
    int e1 = min(e0 + CHUNK, NEDGES);
    for (int i = threadIdx.x; i < NB; i += blockDim.x) { h[i] = 0; lpos[i] = 0; }
    __syncthreads();
    for (int e = e0 + threadIdx.x; e < e1; e += blockDim.x)
        atomicAdd(&h[ei[NEDGES + e] >> BSH], 1);
    __syncthreads();
    for (int i = threadIdx.x; i < NB; i += blockDim.x)
        if (h[i]) base[i] = atomicAdd(&cursor[i], h[i]);
    __syncthreads();
    for (int e = e0 + threadIdx.x; e < e1; e += blockDim.x) {
        int dst = ei[NEDGES + e];
        int b   = dst >> BSH;
        int p   = base[b] + atomicAdd(&lpos[b], 1);
        packed[p] = (unsigned)ei[e] | ((unsigned)(dst & (NPB - 1)) << 20);
    }
}

// ---------- LDS-accumulated scatter, forced 8-deep gather pipeline ----------

__global__ void __launch_bounds__(256, 8) scatter_kernel(
        const float* __restrict__ X, const unsigned int* __restrict__ packed,
        const int* __restrict__ start, float* __restrict__ AGG) {
    __shared__ float tile[NPB * HID];
    int b = blockIdx.x;
    for (int i = threadIdx.x; i < NPB * HID; i += blockDim.x) tile[i] = 0.f;
    __syncthreads();
    int lane = threadIdx.x & 63;
    int wave = threadIdx.x >> 6;
    int nw   = blockDim.x >> 6;
    int eb   = start[b];
    int ee   = start[b + 1];
    for (int base = eb + wave * 64; base < ee; base += nw * 64) {
        int nv = min(64, ee - base);
        unsigned u = (base + lane < ee) ? packed[base + lane] : 0u;
        if (nv == 64) {
#pragma unroll
            for (int k = 0; k < 64; k += 8) {
                float v0 = X[((bcast_u(u, k + 0) & 0xFFFFFu) << 6) + lane];
                float v1 = X[((bcast_u(u, k + 1) & 0xFFFFFu) << 6) + lane];
                float v2 = X[((bcast_u(u, k + 2) & 0xFFFFFu) << 6) + lane];
                float v3 = X[((bcast_u(u, k + 3) & 0xFFFFFu) << 6) + lane];
                float v4 = X[((bcast_u(u, k + 4) & 0xFFFFFu) << 6) + lane];
                float v5 = X[((bcast_u(u, k + 5) & 0xFFFFFu) << 6) + lane];
                float v6 = X[((bcast_u(u, k + 6) & 0xFFFFFu) << 6) + lane];
                float v7 = X[((bcast_u(u, k + 7) & 0xFFFFFu) << 6) + lane];
                // Pin all 8 gathered values live simultaneously: forces the
                // compiler to issue 8 independent loads before any consumer.
                asm volatile("" : "+v"(v0), "+v"(v1), "+v"(v2), "+v"(v3),
                                  "+v"(v4), "+v"(v5), "+v"(v6), "+v"(v7));
                atomicAdd(&tile[((bcast_u(u, k + 0) >> 20) << 6) + lane], v0);
                atomicAdd(&tile[((bcast_u(u, k + 1) >> 20) << 6) + lane], v1);
                atomicAdd(&tile[((bcast_u(u, k + 2) >> 20) << 6) + lane], v2);
                atomicAdd(&tile[((bcast_u(u, k + 3) >> 20) << 6) + lane], v3);
                atomicAdd(&tile[((bcast_u(u, k + 4) >> 20) << 6) + lane], v4);
                atomicAdd(&tile[((bcast_u(u, k + 5) >> 20) << 6) + lane], v5);
                atomicAdd(&tile[((bcast_u(u, k + 6) >> 20) << 6) + lane], v6);
                atomicAdd(&tile[((bcast_u(u, k + 7) >> 20) << 6) + lane], v7);
            }
        } else {
            for (int k = 0; k < nv; ++k) {
                unsigned uj = bcast_u(u, k);
                float vv = X[((uj & 0xFFFFFu) << 6) + lane];
                atomicAdd(&tile[((int)(uj >> 20) << 6) + lane], vv);
            }
        }
    }
    __syncthreads();
    int node0  = b << BSH;
    int nvalid = min(NPB, NNODES - node0);
    for (int i = threadIdx.x; i < nvalid * HID; i += blockDim.x)
        AGG[node0 * HID + i] = tile[i];
}

// ---------- dense pieces (chunked waves + register-pooled graph sums) ----------

__global__ void pre_kernel(const float* __restrict__ xin, const int* __restrict__ batch,
                           const float* __restrict__ w, const float* __restrict__ b,
                           float* __restrict__ X, float* __restrict__ XRES,
                           float* __restrict__ G) {
    __shared__ float sw[INDIM * HID];
    for (int i = threadIdx.x; i < INDIM * HID; i += blockDim.x) sw[i] = w[i];
    __syncthreads();
    int lane = threadIdx.x & 63;
    int wid  = blockIdx.x * (blockDim.x >> 6) + (threadIdx.x >> 6);
    int nW   = gridDim.x * (blockDim.x >> 6);
    int chunk = (NNODES + nW - 1) / nW;
    int n0 = wid * chunk, n1 = min(n0 + chunk, NNODES);
    if (n0 >= n1) return;
    float bb   = b[lane];
    float pool = 0.f;
    int   curg = batch[n0];
    for (int node = n0; node < n1; ++node) {
        float in  = (lane < INDIM) ? xin[node * INDIM + lane] : 0.f;
        float acc = bb;
#pragma unroll
        for (int k = 0; k < INDIM; ++k)
            acc = fmaf(bcast(in, k), sw[k * HID + lane], acc);
        X[node * HID + lane]    = acc;
        XRES[node * HID + lane] = acc;
        int g = batch[node];
        if (g != curg) {
            atomicAdd(&G[curg * CAT + lane], pool);
            pool = 0.f; curg = g;
        }
        pool += acc;
    }
    atomicAdd(&G[curg * CAT + lane], pool);
}

__global__ void mlp_kernel(float* __restrict__ X, const float* __restrict__ AGG,
                           float* __restrict__ XRES, float* __restrict__ G,
                           const int* __restrict__ batch,
                           const float* __restrict__ w1, const float* __restrict__ b1,
                           const float* __restrict__ w2, const float* __restrict__ b2,
                           int do_res, int stage) {
    __shared__ float sw1[HID * HID];
    __shared__ float sw2[HID * HID];
    for (int i = threadIdx.x; i < HID * HID; i += blockDim.x) {
        sw1[i] = w1[i];
        sw2[i] = w2[i];
    }
    __syncthreads();
    int lane = threadIdx.x & 63;
    int wid  = blockIdx.x * (blockDim.x >> 6) + (threadIdx.x >> 6);
    int nW   = gridDim.x * (blockDim.x >> 6);
    int chunk = (NNODES + nW - 1) / nW;
    int n0 = wid * chunk, n1 = min(n0 + chunk, NNODES);
    if (n0 >= n1) return;
    float bb1 = b1[lane], bb2 = b2[lane];
    float pool = 0.f;
    int   curg = batch[n0];
    for (int node = n0; node < n1; ++node) {
        float in   = X[node * HID + lane] + AGG[node * HID + lane];
        float acc1 = bb1;
#pragma unroll
        for (int k = 0; k < HID; ++k)
            acc1 = fmaf(bcast(in, k), sw1[k * HID + lane], acc1);
        float h1   = fmaxf(acc1, 0.f);
        float acc2 = bb2;
#pragma unroll
        for (int k = 0; k < HID; ++k)
            acc2 = fmaf(bcast(h1, k), sw2[k * HID + lane], acc2);
        if (do_res) {
            acc2 += XRES[node * HID + lane];
            XRES[node * HID + lane] = acc2;
        }
        float xn = fmaxf(acc2, 0.f);
        X[node * HID + lane] = xn;
        int g = batch[node];
        if (g != curg) {
            atomicAdd(&G[curg * CAT + stage * HID + lane], pool);
            pool = 0.f; curg = g;
        }
        pool += xn;
    }
    atomicAdd(&G[curg * CAT + stage * HID + lane], pool);
}

__global__ void post_kernel(const float* __restrict__ GQ, const float* __restrict__ GC,
                            const float* __restrict__ w1, const float* __restrict__ b1,
                            const float* __restrict__ w2, const float* __restrict__ b2,
                            float* __restrict__ out) {
    int g    = blockIdx.x;
    int lane = threadIdx.x;
    __shared__ float h1q[HID], h1c[HID];
    float aq = b1[lane], ac = b1[lane];
    for (int k = 0; k < CAT; ++k) {
        float w = w1[k * HID + lane];
        aq = fmaf(GQ[g * CAT + k], w, aq);
        ac = fmaf(GC[g * CAT + k], w, ac);
    }
    h1q[lane] = fmaxf(aq, 0.f);
    h1c[lane] = fmaxf(ac, 0.f);
    __syncthreads();
    float s = 0.f;
    if (lane < ODIM) {
        float oq = b2[lane], oc = b2[lane];
        for (int k = 0; k < HID; ++k) {
            float w = w2[k * ODIM + lane];
            oq = fmaf(h1q[k], w, oq);
            oc = fmaf(h1c[k], w, oc);
        }
        s = fabsf(oq - oc);
    }
    for (int off = 16; off; off >>= 1) s += __shfl_down(s, off, 64);
    if (lane == 0) out[g] = s;
}

extern "C" void kernel_launch(void* const* d_in, const int* in_sizes, int n_in,
                              void* d_out, int out_size, void* d_ws, size_t ws_size,
                              hipStream_t stream) {
    const float* x_q     = (const float*)d_in[0];
    const int*   ei_q    = (const int*)d_in[1];
    const int*   batch_q = (const int*)d_in[2];
    const float* x_c     = (const float*)d_in[3];
    const int*   ei_c    = (const int*)d_in[4];
    const int*   batch_c = (const int*)d_in[5];
    const float* pre_w   = (const float*)d_in[6];
    const float* pre_b   = (const float*)d_in[7];
    const float* conv_w1 = (const float*)d_in[8];
    const float* conv_b1 = (const float*)d_in[9];
    const float* conv_w2 = (const float*)d_in[10];
    const float* conv_b2 = (const float*)d_in[11];
    const float* post_w1 = (const float*)d_in[12];
    const float* post_b1 = (const float*)d_in[13];
    const float* post_w2 = (const float*)d_in[14];
    const float* post_b2 = (const float*)d_in[15];

    float* ws   = (float*)d_ws;
    float* X    = ws;                       // NNODES*HID
    float* AGG  = X + NNODES * HID;         // NNODES*HID
    float* XRES = AGG + NNODES * HID;       // NNODES*HID
    float* GQ   = XRES + NNODES * HID;      // NG*CAT
    float* GC   = GQ + NG * CAT;            // NG*CAT
    int*   counts = (int*)(GC + NG * CAT);  // NB
    int*   start  = counts + NB;            // NB+1
    int*   cursor = start + NB + 1;         // NB
    unsigned int* packed = (unsigned int*)(cursor + NB);  // NEDGES

    hipMemsetAsync(GQ, 0, 2 * NG * CAT * sizeof(float), stream);

    for (int side = 0; side < 2; ++side) {
        const float* xin   = side ? x_c : x_q;
        const int*   ei    = side ? ei_c : ei_q;
        const int*   batch = side ? batch_c : batch_q;
        float*       G     = side ? GC : GQ;

        hipMemsetAsync(counts, 0, NB * sizeof(int), stream);
        hist_kernel<<<256, 256, 0, stream>>>(ei, counts);
        scan_kernel<<<1, 1024, 0, stream>>>(counts, start, cursor);
        reorder_kernel<<<NCHUNKBLKS, 256, 0, stream>>>(ei, cursor, packed);

        pre_kernel<<<1024, 256, 0, stream>>>(xin, batch, pre_w, pre_b, X, XRES, G);

        for (int l = 0; l < 4; ++l) {
            scatter_kernel<<<NB, 256, 0, stream>>>(X, packed, start, AGG);
            mlp_kernel<<<1024, 256, 0, stream>>>(X, AGG, XRES, G, batch,
                                                 conv_w1 + l * HID * HID, conv_b1 + l * HID,
                                                 conv_w2 + l * HID * HID, conv_b2 + l * HID,
                                                 l & 1, l + 1);
        }
    }

    post_kernel<<<NG, 64, 0, stream>>>(GQ, GC, post_w1, post_b1, post_w2, post_b2,
                                       (float*)d_out);
}

// Round 5
// 2385.648 us; speedup vs baseline: 5.1552x; 2.4129x over previous
//
#include <hip/hip_runtime.h>

#define NNODES 100000
#define NEDGES 1600000
#define NG 128
#define HID 64
#define INDIM 32
#define CAT 320   // HID*(L+1)
#define ODIM 32

#define BSH 6                              // nodes per tile = 64
#define NPB 64
#define NB ((NNODES + NPB - 1) / NPB)      // 1563

__device__ __forceinline__ float bcast(float v, int lane) {
    return __uint_as_float(__builtin_amdgcn_readlane(__float_as_uint(v), lane));
}
__device__ __forceinline__ unsigned bcast_u(unsigned v, int lane) {
    return __builtin_amdgcn_readlane(v, lane);
}

// ---------- full counting sort of edges by dst (once per side) ----------

__global__ void hist_kernel(const int* __restrict__ ei, int* __restrict__ counts) {
    int stride = gridDim.x * blockDim.x;
    for (int e = blockIdx.x * blockDim.x + threadIdx.x; e < NEDGES; e += stride)
        atomicAdd(&counts[ei[NEDGES + e]], 1);
}

// single block, 1024 threads, 98 contiguous counters per thread
__global__ void scan_kernel(const int* __restrict__ counts, int* __restrict__ start,
                            int* __restrict__ cursor) {
    __shared__ int s[1024];
    int t = threadIdx.x;
    const int PER = (NNODES + 1023) / 1024;   // 98
    int i0 = t * PER;
    int i1 = min(i0 + PER, NNODES);
    int sum = 0;
    for (int i = i0; i < i1; ++i) sum += counts[i];
    s[t] = sum;
    for (int off = 1; off < 1024; off <<= 1) {
        __syncthreads();
        int v = (t >= off) ? s[t - off] : 0;
        __syncthreads();
        s[t] += v;
    }
    __syncthreads();
    int run = s[t] - sum;
    for (int i = i0; i < i1; ++i) {
        start[i] = run;
        cursor[i] = run;
        run += counts[i];
    }
    if (t == 0) start[NNODES] = NEDGES;
}

__global__ void reorder_kernel(const int* __restrict__ ei, int* __restrict__ cursor,
                               unsigned* __restrict__ packed) {
    int stride = gridDim.x * blockDim.x;
    for (int e = blockIdx.x * blockDim.x + threadIdx.x; e < NEDGES; e += stride) {
        int dst = ei[NEDGES + e];
        int p = atomicAdd(&cursor[dst], 1);
        packed[p] = (unsigned)ei[e] | ((unsigned)(dst & (NPB - 1)) << 20);
    }
}

// ---------- scatter: forced 16-deep asm gather pipeline + run-accumulate ----------

#define LOADV(vv, kk) { \
    const float* ap_ = X + (((size_t)(bcast_u(u, (kk)) & 0xFFFFFu)) << 6) + lane; \
    asm volatile("global_load_dword %0, %1, off" : "=v"(vv) : "v"(ap_)); }

#define PROCJ(vv, kk, cnt) { \
    asm volatile("s_waitcnt vmcnt(" #cnt ")" ::: "memory"); \
    __builtin_amdgcn_sched_barrier(0); \
    int ld_ = (int)(bcast_u(u, (kk)) >> 20); \
    if (ld_ != cur) { \
        if (cur >= 0) atomicAdd(&tile[(cur << 6) + lane], acc); \
        acc = 0.f; cur = ld_; \
    } \
    acc += (vv); }

#define LOAD8(P, base) \
    LOADV(P##0, (base)+0) LOADV(P##1, (base)+1) LOADV(P##2, (base)+2) LOADV(P##3, (base)+3) \
    LOADV(P##4, (base)+4) LOADV(P##5, (base)+5) LOADV(P##6, (base)+6) LOADV(P##7, (base)+7)

#define PROC8_HI(P, base) \
    PROCJ(P##0,(base)+0,15) PROCJ(P##1,(base)+1,14) PROCJ(P##2,(base)+2,13) PROCJ(P##3,(base)+3,12) \
    PROCJ(P##4,(base)+4,11) PROCJ(P##5,(base)+5,10) PROCJ(P##6,(base)+6,9)  PROCJ(P##7,(base)+7,8)

#define PROC8_LO(P, base) \
    PROCJ(P##0,(base)+0,7) PROCJ(P##1,(base)+1,6) PROCJ(P##2,(base)+2,5) PROCJ(P##3,(base)+3,4) \
    PROCJ(P##4,(base)+4,3) PROCJ(P##5,(base)+5,2) PROCJ(P##6,(base)+6,1) PROCJ(P##7,(base)+7,0)

__global__ void __launch_bounds__(256) scatter_kernel(
        const float* __restrict__ X, const unsigned* __restrict__ packed,
        const int* __restrict__ start, float* __restrict__ AGG) {
    __shared__ float tile[NPB * HID];
    int blk = blockIdx.x;
    for (int i = threadIdx.x; i < NPB * HID; i += blockDim.x) tile[i] = 0.f;
    __syncthreads();
    int lane   = threadIdx.x & 63;
    int wave   = threadIdx.x >> 6;
    int nw     = blockDim.x >> 6;
    int node0  = blk << BSH;
    int nvalid = min(NPB, NNODES - node0);
    int eb = start[node0];
    int ee = start[node0 + nvalid];
    for (int base = eb + wave * 64; base < ee; base += nw * 64) {
        int nv = min(64, ee - base);
        unsigned u = (base + lane < ee) ? packed[base + lane] : 0u;
        float acc = 0.f;
        int   cur = -1;
        if (nv == 64) {
            float p0,p1,p2,p3,p4,p5,p6,p7, q0,q1,q2,q3,q4,q5,q6,q7;
            LOAD8(p, 0)
            LOAD8(q, 8)
            PROC8_HI(p, 0)
            LOAD8(p, 16)
            PROC8_HI(q, 8)
            LOAD8(q, 24)
            PROC8_HI(p, 16)
            LOAD8(p, 32)
            PROC8_HI(q, 24)
            LOAD8(q, 40)
            PROC8_HI(p, 32)
            LOAD8(p, 48)
            PROC8_HI(q, 40)
            LOAD8(q, 56)
            PROC8_HI(p, 48)
            PROC8_LO(q, 56)
        } else {
            for (int k = 0; k < nv; ++k) {
                unsigned uj = bcast_u(u, k);
                float vv = X[((size_t)(uj & 0xFFFFFu) << 6) + lane];
                atomicAdd(&tile[((uj >> 20) << 6) + lane], vv);
            }
        }
        if (cur >= 0) atomicAdd(&tile[(cur << 6) + lane], acc);
    }
    __syncthreads();
    const float4* t4 = (const float4*)tile;
    float4* a4 = (float4*)(AGG + ((size_t)node0 << 6));
    for (int i = threadIdx.x; i < nvalid * (HID / 4); i += blockDim.x) a4[i] = t4[i];
}

// ---------- dense pieces (chunked waves + register-pooled graph sums) ----------

__global__ void pre_kernel(const float* __restrict__ xin, const int* __restrict__ batch,
                           const float* __restrict__ w, const float* __restrict__ b,
                           float* __restrict__ X, float* __restrict__ XRES,
                           float* __restrict__ G) {
    __shared__ float sw[INDIM * HID];
    for (int i = threadIdx.x; i < INDIM * HID; i += blockDim.x) sw[i] = w[i];
    __syncthreads();
    int lane = threadIdx.x & 63;
    int wid  = blockIdx.x * (blockDim.x >> 6) + (threadIdx.x >> 6);
    int nW   = gridDim.x * (blockDim.x >> 6);
    int chunk = (NNODES + nW - 1) / nW;
    int n0 = wid * chunk, n1 = min(n0 + chunk, NNODES);
    if (n0 >= n1) return;
    float bb   = b[lane];
    float pool = 0.f;
    int   curg = batch[n0];
    for (int node = n0; node < n1; ++node) {
        float in  = (lane < INDIM) ? xin[node * INDIM + lane] : 0.f;
        float acc = bb;
#pragma unroll
        for (int k = 0; k < INDIM; ++k)
            acc = fmaf(bcast(in, k), sw[k * HID + lane], acc);
        X[node * HID + lane]    = acc;
        XRES[node * HID + lane] = acc;
        int g = batch[node];
        if (g != curg) {
            atomicAdd(&G[curg * CAT + lane], pool);
            pool = 0.f; curg = g;
        }
        pool += acc;
    }
    atomicAdd(&G[curg * CAT + lane], pool);
}

__global__ void mlp_kernel(float* __restrict__ X, const float* __restrict__ AGG,
                           float* __restrict__ XRES, float* __restrict__ G,
                           const int* __restrict__ batch,
                           const float* __restrict__ w1, const float* __restrict__ b1,
                           const float* __restrict__ w2, const float* __restrict__ b2,
                           int do_res, int stage) {
    __shared__ float sw1[HID * HID];
    __shared__ float sw2[HID * HID];
    for (int i = threadIdx.x; i < HID * HID; i += blockDim.x) {
        sw1[i] = w1[i];
        sw2[i] = w2[i];
    }
    __syncthreads();
    int lane = threadIdx.x & 63;
    int wid  = blockIdx.x * (blockDim.x >> 6) + (threadIdx.x >> 6);
    int nW   = gridDim.x * (blockDim.x >> 6);
    int chunk = (NNODES + nW - 1) / nW;
    int n0 = wid * chunk, n1 = min(n0 + chunk, NNODES);
    if (n0 >= n1) return;
    float bb1 = b1[lane], bb2 = b2[lane];
    float pool = 0.f;
    int   curg = batch[n0];
    for (int node = n0; node < n1; ++node) {
        float in   = X[node * HID + lane] + AGG[node * HID + lane];
        float acc1 = bb1;
#pragma unroll
        for (int k = 0; k < HID; ++k)
            acc1 = fmaf(bcast(in, k), sw1[k * HID + lane], acc1);
        float h1   = fmaxf(acc1, 0.f);
        float acc2 = bb2;
#pragma unroll
        for (int k = 0; k < HID; ++k)
            acc2 = fmaf(bcast(h1, k), sw2[k * HID + lane], acc2);
        if (do_res) {
            acc2 += XRES[node * HID + lane];
            XRES[node * HID + lane] = acc2;
        }
        float xn = fmaxf(acc2, 0.f);
        X[node * HID + lane] = xn;
        int g = batch[node];
        if (g != curg) {
            atomicAdd(&G[curg * CAT + stage * HID + lane], pool);
            pool = 0.f; curg = g;
        }
        pool += xn;
    }
    atomicAdd(&G[curg * CAT + stage * HID + lane], pool);
}

__global__ void post_kernel(const float* __restrict__ GQ, const float* __restrict__ GC,
                            const float* __restrict__ w1, const float* __restrict__ b1,
                            const float* __restrict__ w2, const float* __restrict__ b2,
                            float* __restrict__ out) {
    int g    = blockIdx.x;
    int lane = threadIdx.x;
    __shared__ float h1q[HID], h1c[HID];
    float aq = b1[lane], ac = b1[lane];
    for (int k = 0; k < CAT; ++k) {
        float w = w1[k * HID + lane];
        aq = fmaf(GQ[g * CAT + k], w, aq);
        ac = fmaf(GC[g * CAT + k], w, ac);
    }
    h1q[lane] = fmaxf(aq, 0.f);
    h1c[lane] = fmaxf(ac, 0.f);
    __syncthreads();
    float s = 0.f;
    if (lane < ODIM) {
        float oq = b2[lane], oc = b2[lane];
        for (int k = 0; k < HID; ++k) {
            float w = w2[k * ODIM + lane];
            oq = fmaf(h1q[k], w, oq);
            oc = fmaf(h1c[k], w, oc);
        }
        s = fabsf(oq - oc);
    }
    for (int off = 16; off; off >>= 1) s += __shfl_down(s, off, 64);
    if (lane == 0) out[g] = s;
}

extern "C" void kernel_launch(void* const* d_in, const int* in_sizes, int n_in,
                              void* d_out, int out_size, void* d_ws, size_t ws_size,
                              hipStream_t stream) {
    const float* x_q     = (const float*)d_in[0];
    const int*   ei_q    = (const int*)d_in[1];
    const int*   batch_q = (const int*)d_in[2];
    const float* x_c     = (const float*)d_in[3];
    const int*   ei_c    = (const int*)d_in[4];
    const int*   batch_c = (const int*)d_in[5];
    const float* pre_w   = (const float*)d_in[6];
    const float* pre_b   = (const float*)d_in[7];
    const float* conv_w1 = (const float*)d_in[8];
    const float* conv_b1 = (const float*)d_in[9];
    const float* conv_w2 = (const float*)d_in[10];
    const float* conv_b2 = (const float*)d_in[11];
    const float* post_w1 = (const float*)d_in[12];
    const float* post_b1 = (const float*)d_in[13];
    const float* post_w2 = (const float*)d_in[14];
    const float* post_b2 = (const float*)d_in[15];

    float* ws   = (float*)d_ws;
    float* X    = ws;                       // NNODES*HID
    float* AGG  = X + NNODES * HID;         // NNODES*HID
    float* XRES = AGG + NNODES * HID;       // NNODES*HID
    float* GQ   = XRES + NNODES * HID;      // NG*CAT
    float* GC   = GQ + NG * CAT;            // NG*CAT
    int*   counts = (int*)(GC + NG * CAT);  // NNODES
    int*   start  = counts + NNODES;        // NNODES+1
    int*   cursor = start + NNODES + 1;     // NNODES
    unsigned* packed = (unsigned*)(cursor + NNODES);  // NEDGES

    hipMemsetAsync(GQ, 0, 2 * NG * CAT * sizeof(float), stream);

    for (int side = 0; side < 2; ++side) {
        const float* xin   = side ? x_c : x_q;
        const int*   ei    = side ? ei_c : ei_q;
        const int*   batch = side ? batch_c : batch_q;
        float*       G     = side ? GC : GQ;

        hipMemsetAsync(counts, 0, NNODES * sizeof(int), stream);
        hist_kernel<<<2048, 256, 0, stream>>>(ei, counts);
        scan_kernel<<<1, 1024, 0, stream>>>(counts, start, cursor);
        reorder_kernel<<<2048, 256, 0, stream>>>(ei, cursor, packed);

        pre_kernel<<<1024, 256, 0, stream>>>(xin, batch, pre_w, pre_b, X, XRES, G);

        for (int l = 0; l < 4; ++l) {
            scatter_kernel<<<NB, 256, 0, stream>>>(X, packed, start, AGG);
            mlp_kernel<<<1024, 256, 0, stream>>>(X, AGG, XRES, G, batch,
                                                 conv_w1 + l * HID * HID, conv_b1 + l * HID,
                                                 conv_w2 + l * HID * HID, conv_b2 + l * HID,
                                                 l & 1, l + 1);
        }
    }

    post_kernel<<<NG, 64, 0, stream>>>(GQ, GC, post_w1, post_b1, post_w2, post_b2,
                                       (float*)d_out);
}

// Round 6
// 1748.539 us; speedup vs baseline: 7.0336x; 1.3644x over previous
//
#include <hip/hip_runtime.h>

#define NNODES 100000
#define NEDGES 1600000
#define NG 128
#define HID 64
#define INDIM 32
#define CAT 320   // HID*(L+1)
#define ODIM 32

#define BSH 6                              // nodes per tile = 64
#define NPB 64
#define NB ((NNODES + NPB - 1) / NPB)      // 1563

#define SCAN_BLK 1024
#define NSCAN ((NNODES + SCAN_BLK - 1) / SCAN_BLK)   // 98

__device__ __forceinline__ float bcast(float v, int lane) {
    return __uint_as_float(__builtin_amdgcn_readlane(__float_as_uint(v), lane));
}
__device__ __forceinline__ unsigned bcast_u(unsigned v, int lane) {
    return __builtin_amdgcn_readlane(v, lane);
}

// ---------- full counting sort of edges by dst (once per side) ----------

__global__ void hist_kernel(const int* __restrict__ ei, int* __restrict__ counts) {
    int stride = gridDim.x * blockDim.x;
    for (int e = blockIdx.x * blockDim.x + threadIdx.x; e < NEDGES; e += stride)
        atomicAdd(&counts[ei[NEDGES + e]], 1);
}

// hierarchical scan: block-local exclusive scan + block sums
__global__ void scan1_kernel(const int* __restrict__ counts, int* __restrict__ start,
                             int* __restrict__ bsums) {
    __shared__ int s[SCAN_BLK];
    int t = threadIdx.x;
    int i = blockIdx.x * SCAN_BLK + t;
    int v = (i < NNODES) ? counts[i] : 0;
    s[t] = v;
    for (int off = 1; off < SCAN_BLK; off <<= 1) {
        __syncthreads();
        int a = (t >= off) ? s[t - off] : 0;
        __syncthreads();
        s[t] += a;
    }
    __syncthreads();
    if (i < NNODES) start[i] = s[t] - v;        // block-local exclusive
    if (t == SCAN_BLK - 1) bsums[blockIdx.x] = s[t];
}

__global__ void scan2_kernel(int* __restrict__ bsums) {
    __shared__ int s[128];
    int t = threadIdx.x;
    int v = (t < NSCAN) ? bsums[t] : 0;
    s[t] = v;
    for (int off = 1; off < 128; off <<= 1) {
        __syncthreads();
        int a = (t >= off) ? s[t - off] : 0;
        __syncthreads();
        s[t] += a;
    }
    __syncthreads();
    if (t < NSCAN) bsums[t] = s[t] - v;         // exclusive block offsets
}

__global__ void scan3_kernel(int* __restrict__ start, int* __restrict__ cursor,
                             const int* __restrict__ bsums) {
    int i = blockIdx.x * SCAN_BLK + threadIdx.x;
    if (i < NNODES) {
        int v = start[i] + bsums[blockIdx.x];
        start[i]  = v;
        cursor[i] = v;
    }
    if (i == 0) start[NNODES] = NEDGES;
}

__global__ void reorder_kernel(const int* __restrict__ ei, int* __restrict__ cursor,
                               unsigned* __restrict__ packed) {
    int stride = gridDim.x * blockDim.x;
    for (int e = blockIdx.x * blockDim.x + threadIdx.x; e < NEDGES; e += stride) {
        int dst = ei[NEDGES + e];
        int p = atomicAdd(&cursor[dst], 1);
        packed[p] = (unsigned)ei[e] | ((unsigned)(dst & (NPB - 1)) << 20);
    }
}

// ---------- fused gather + GIN-MLP layer (ping-pong X buffers) ----------

#define LOADV(vv, kk) { \
    const float* ap_ = X + (((size_t)(bcast_u(u, (kk)) & 0xFFFFFu)) << 6) + lane; \
    asm volatile("global_load_dword %0, %1, off" : "=v"(vv) : "v"(ap_)); }

#define PROCJ(vv, kk, cnt) { \
    asm volatile("s_waitcnt vmcnt(" #cnt ")" ::: "memory"); \
    __builtin_amdgcn_sched_barrier(0); \
    int ld_ = (int)(bcast_u(u, (kk)) >> 20); \
    if (ld_ != cur) { \
        if (cur >= 0) atomicAdd(&tile[(cur << 6) + lane], acc); \
        acc = 0.f; cur = ld_; \
    } \
    acc += (vv); }

#define LOAD8(P, base) \
    LOADV(P##0, (base)+0) LOADV(P##1, (base)+1) LOADV(P##2, (base)+2) LOADV(P##3, (base)+3) \
    LOADV(P##4, (base)+4) LOADV(P##5, (base)+5) LOADV(P##6, (base)+6) LOADV(P##7, (base)+7)

#define PROC8_HI(P, base) \
    PROCJ(P##0,(base)+0,15) PROCJ(P##1,(base)+1,14) PROCJ(P##2,(base)+2,13) PROCJ(P##3,(base)+3,12) \
    PROCJ(P##4,(base)+4,11) PROCJ(P##5,(base)+5,10) PROCJ(P##6,(base)+6,9)  PROCJ(P##7,(base)+7,8)

#define PROC8_LO(P, base) \
    PROCJ(P##0,(base)+0,7) PROCJ(P##1,(base)+1,6) PROCJ(P##2,(base)+2,5) PROCJ(P##3,(base)+3,4) \
    PROCJ(P##4,(base)+4,3) PROCJ(P##5,(base)+5,2) PROCJ(P##6,(base)+6,1) PROCJ(P##7,(base)+7,0)

__global__ void __launch_bounds__(256) fused_kernel(
        const float* __restrict__ Xin, float* __restrict__ Xout,
        float* __restrict__ XRES, float* __restrict__ G,
        const int* __restrict__ batch,
        const unsigned* __restrict__ packed, const int* __restrict__ start,
        const float* __restrict__ w1, const float* __restrict__ b1,
        const float* __restrict__ w2, const float* __restrict__ b2,
        int do_res, int stage) {
    __shared__ float tile[NPB * HID];
    __shared__ float sw1[HID * HID];
    __shared__ float sw2[HID * HID];
    const float* X = Xin;
    int blk = blockIdx.x;
    for (int i = threadIdx.x; i < NPB * HID; i += blockDim.x) tile[i] = 0.f;
    for (int i = threadIdx.x; i < HID * HID; i += blockDim.x) {
        sw1[i] = w1[i];
        sw2[i] = w2[i];
    }
    __syncthreads();
    int lane   = threadIdx.x & 63;
    int wave   = threadIdx.x >> 6;
    int nw     = blockDim.x >> 6;
    int node0  = blk << BSH;
    int nvalid = min(NPB, NNODES - node0);
    int eb = start[node0];
    int ee = start[node0 + nvalid];
    // ---- gather phase: forced 16-deep asm pipeline + sorted-run accumulate ----
    for (int base = eb + wave * 64; base < ee; base += nw * 64) {
        int nv = min(64, ee - base);
        unsigned u = (base + lane < ee) ? packed[base + lane] : 0u;
        float acc = 0.f;
        int   cur = -1;
        if (nv == 64) {
            float p0,p1,p2,p3,p4,p5,p6,p7, q0,q1,q2,q3,q4,q5,q6,q7;
            LOAD8(p, 0)
            LOAD8(q, 8)
            PROC8_HI(p, 0)
            LOAD8(p, 16)
            PROC8_HI(q, 8)
            LOAD8(q, 24)
            PROC8_HI(p, 16)
            LOAD8(p, 32)
            PROC8_HI(q, 24)
            LOAD8(q, 40)
            PROC8_HI(p, 32)
            LOAD8(p, 48)
            PROC8_HI(q, 40)
            LOAD8(q, 56)
            PROC8_HI(p, 48)
            PROC8_LO(q, 56)
        } else {
            for (int k = 0; k < nv; ++k) {
                unsigned uj = bcast_u(u, k);
                float vv = X[((size_t)(uj & 0xFFFFFu) << 6) + lane];
                atomicAdd(&tile[((uj >> 20) << 6) + lane], vv);
            }
        }
        if (cur >= 0) atomicAdd(&tile[(cur << 6) + lane], acc);
    }
    __syncthreads();
    // ---- MLP phase: wave w owns 16 contiguous nodes of the tile ----
    int per = NPB >> 2;                         // 16 nodes per wave
    int n0w = node0 + wave * per;
    int n1w = min(n0w + per, node0 + nvalid);
    if (n0w < n1w) {
        float bb1 = b1[lane], bb2 = b2[lane];
        float pool = 0.f;
        int   curg = batch[n0w];
        for (int node = n0w; node < n1w; ++node) {
            float in   = Xin[((size_t)node << 6) + lane] + tile[((node - node0) << 6) + lane];
            float acc1 = bb1;
#pragma unroll
            for (int k = 0; k < HID; ++k)
                acc1 = fmaf(bcast(in, k), sw1[k * HID + lane], acc1);
            float h1   = fmaxf(acc1, 0.f);
            float acc2 = bb2;
#pragma unroll
            for (int k = 0; k < HID; ++k)
                acc2 = fmaf(bcast(h1, k), sw2[k * HID + lane], acc2);
            if (do_res) {
                acc2 += XRES[((size_t)node << 6) + lane];
                XRES[((size_t)node << 6) + lane] = acc2;
            }
            float xn = fmaxf(acc2, 0.f);
            Xout[((size_t)node << 6) + lane] = xn;
            int g = batch[node];
            if (g != curg) {
                atomicAdd(&G[curg * CAT + stage * HID + lane], pool);
                pool = 0.f; curg = g;
            }
            pool += xn;
        }
        atomicAdd(&G[curg * CAT + stage * HID + lane], pool);
    }
}

// ---------- dense pieces ----------

__global__ void pre_kernel(const float* __restrict__ xin, const int* __restrict__ batch,
                           const float* __restrict__ w, const float* __restrict__ b,
                           float* __restrict__ X, float* __restrict__ XRES,
                           float* __restrict__ G) {
    __shared__ float sw[INDIM * HID];
    for (int i = threadIdx.x; i < INDIM * HID; i += blockDim.x) sw[i] = w[i];
    __syncthreads();
    int lane = threadIdx.x & 63;
    int wid  = blockIdx.x * (blockDim.x >> 6) + (threadIdx.x >> 6);
    int nW   = gridDim.x * (blockDim.x >> 6);
    int chunk = (NNODES + nW - 1) / nW;
    int n0 = wid * chunk, n1 = min(n0 + chunk, NNODES);
    if (n0 >= n1) return;
    float bb   = b[lane];
    float pool = 0.f;
    int   curg = batch[n0];
    for (int node = n0; node < n1; ++node) {
        float in  = (lane < INDIM) ? xin[node * INDIM + lane] : 0.f;
        float acc = bb;
#pragma unroll
        for (int k = 0; k < INDIM; ++k)
            acc = fmaf(bcast(in, k), sw[k * HID + lane], acc);
        X[node * HID + lane]    = acc;
        XRES[node * HID + lane] = acc;
        int g = batch[node];
        if (g != curg) {
            atomicAdd(&G[curg * CAT + lane], pool);
            pool = 0.f; curg = g;
        }
        pool += acc;
    }
    atomicAdd(&G[curg * CAT + lane], pool);
}

__global__ void post_kernel(const float* __restrict__ GQ, const float* __restrict__ GC,
                            const float* __restrict__ w1, const float* __restrict__ b1,
                            const float* __restrict__ w2, const float* __restrict__ b2,
                            float* __restrict__ out) {
    int g    = blockIdx.x;
    int lane = threadIdx.x;
    __shared__ float h1q[HID], h1c[HID];
    float aq = b1[lane], ac = b1[lane];
    for (int k = 0; k < CAT; ++k) {
        float w = w1[k * HID + lane];
        aq = fmaf(GQ[g * CAT + k], w, aq);
        ac = fmaf(GC[g * CAT + k], w, ac);
    }
    h1q[lane] = fmaxf(aq, 0.f);
    h1c[lane] = fmaxf(ac, 0.f);
    __syncthreads();
    float s = 0.f;
    if (lane < ODIM) {
        float oq = b2[lane], oc = b2[lane];
        for (int k = 0; k < HID; ++k) {
            float w = w2[k * ODIM + lane];
            oq = fmaf(h1q[k], w, oq);
            oc = fmaf(h1c[k], w, oc);
        }
        s = fabsf(oq - oc);
    }
    for (int off = 16; off; off >>= 1) s += __shfl_down(s, off, 64);
    if (lane == 0) out[g] = s;
}

extern "C" void kernel_launch(void* const* d_in, const int* in_sizes, int n_in,
                              void* d_out, int out_size, void* d_ws, size_t ws_size,
                              hipStream_t stream) {
    const float* x_q     = (const float*)d_in[0];
    const int*   ei_q    = (const int*)d_in[1];
    const int*   batch_q = (const int*)d_in[2];
    const float* x_c     = (const float*)d_in[3];
    const int*   ei_c    = (const int*)d_in[4];
    const int*   batch_c = (const int*)d_in[5];
    const float* pre_w   = (const float*)d_in[6];
    const float* pre_b   = (const float*)d_in[7];
    const float* conv_w1 = (const float*)d_in[8];
    const float* conv_b1 = (const float*)d_in[9];
    const float* conv_w2 = (const float*)d_in[10];
    const float* conv_b2 = (const float*)d_in[11];
    const float* post_w1 = (const float*)d_in[12];
    const float* post_b1 = (const float*)d_in[13];
    const float* post_w2 = (const float*)d_in[14];
    const float* post_b2 = (const float*)d_in[15];

    float* ws   = (float*)d_ws;
    float* XA   = ws;                       // NNODES*HID
    float* XB   = XA + NNODES * HID;        // NNODES*HID
    float* XRES = XB + NNODES * HID;        // NNODES*HID
    float* GQ   = XRES + NNODES * HID;      // NG*CAT
    float* GC   = GQ + NG * CAT;            // NG*CAT
    int*   counts = (int*)(GC + NG * CAT);  // NNODES
    int*   start  = counts + NNODES;        // NNODES+1
    int*   cursor = start + NNODES + 1;     // NNODES
    unsigned* packed = (unsigned*)(cursor + NNODES);  // NEDGES
    int*   bsums  = (int*)(packed + NEDGES);          // NSCAN

    hipMemsetAsync(GQ, 0, 2 * NG * CAT * sizeof(float), stream);

    for (int side = 0; side < 2; ++side) {
        const float* xin   = side ? x_c : x_q;
        const int*   ei    = side ? ei_c : ei_q;
        const int*   batch = side ? batch_c : batch_q;
        float*       G     = side ? GC : GQ;

        hipMemsetAsync(counts, 0, NNODES * sizeof(int), stream);
        hist_kernel<<<2048, 256, 0, stream>>>(ei, counts);
        scan1_kernel<<<NSCAN, SCAN_BLK, 0, stream>>>(counts, start, bsums);
        scan2_kernel<<<1, 128, 0, stream>>>(bsums);
        scan3_kernel<<<NSCAN, SCAN_BLK, 0, stream>>>(start, cursor, bsums);
        reorder_kernel<<<2048, 256, 0, stream>>>(ei, cursor, packed);

        pre_kernel<<<1024, 256, 0, stream>>>(xin, batch, pre_w, pre_b, XA, XRES, G);

        float* xcur = XA;
        float* xnxt = XB;
        for (int l = 0; l < 4; ++l) {
            fused_kernel<<<NB, 256, 0, stream>>>(xcur, xnxt, XRES, G, batch, packed, start,
                                                 conv_w1 + l * HID * HID, conv_b1 + l * HID,
                                                 conv_w2 + l * HID * HID, conv_b2 + l * HID,
                                                 l & 1, l + 1);
            float* t = xcur; xcur = xnxt; xnxt = t;
        }
    }

    post_kernel<<<NG, 64, 0, stream>>>(GQ, GC, post_w1, post_b1, post_w2, post_b2,
                                       (float*)d_out);
}